// Round 8
// baseline (70.942 us; speedup 1.0000x reference)
//
#include <hip/hip_runtime.h>

#define N_NODES 8192
#define NNZV    262144
#define E_EDGES 32768
#define PSI     64
#define NTHR    256

typedef float f32x4 __attribute__((ext_vector_type(4)));

// Stage 1: edge_feat = MLP(values) ; atomic scatter-add into agg[col]
__global__ void edge_mlp_scatter(const int* __restrict__ col,
                                 const float* __restrict__ values,
                                 const float* __restrict__ w1e,
                                 const float* __restrict__ b1e,
                                 const float* __restrict__ w2e,
                                 const float* __restrict__ b2e,
                                 float* __restrict__ agg) {
    __shared__ float sw1[PSI], sb1[PSI], sw2[PSI];
    int t = threadIdx.x;
    if (t < PSI) { sw1[t] = w1e[t]; sb1[t] = b1e[t]; sw2[t] = w2e[t]; }
    __syncthreads();
    int i = blockIdx.x * blockDim.x + t;
    if (i >= NNZV) return;
    float v = values[i];
    float f = b2e[0];
    #pragma unroll
    for (int j = 0; j < PSI; ++j) {
        float h = fmaf(v, sw1[j], sb1[j]);
        f += (h > 0.f ? h * sw2[j] : 0.f);
    }
    atomicAdd(&agg[col[i]], f);
}

// Stage 2: struct = MLP(agg) ; store struct^2
__global__ void node_mlp_sq(const float* __restrict__ agg,
                            const float* __restrict__ w1n,
                            const float* __restrict__ b1n,
                            const float* __restrict__ w2n,
                            const float* __restrict__ b2n,
                            float* __restrict__ s2) {
    __shared__ float sw1[PSI], sb1[PSI], sw2[PSI];
    int t = threadIdx.x;
    if (t < PSI) { sw1[t] = w1n[t]; sb1[t] = b1n[t]; sw2[t] = w2n[t]; }
    __syncthreads();
    int n = blockIdx.x * blockDim.x + t;
    if (n >= N_NODES) return;
    float a = agg[n];
    float s = b2n[0];
    #pragma unroll
    for (int j = 0; j < PSI; ++j) {
        float h = fmaf(a, sw1[j], sb1[j]);
        s += (h > 0.f ? h * sw2[j] : 0.f);
    }
    s2[n] = s * s;
}

// Stage 3: wave-per-row. Each 64-lane wave owns one row: 32 f32x4 loads/lane,
// pure shuffle reduction — no LDS, no __syncthreads, no cross-wave tail.
// __launch_bounds__(256,8): VGPR<=64 so the full 32 waves/CU stay resident.
__global__ __launch_bounds__(NTHR, 8) void row_dot_wave(const float* __restrict__ adj,
                                                        const float* __restrict__ s2,
                                                        float* __restrict__ r) {
    const int lane = threadIdx.x & 63;
    const int wid  = threadIdx.x >> 6;
    const int row  = blockIdx.x * 4 + wid;

    const f32x4* arow = (const f32x4*)(adj + (size_t)row * N_NODES);
    const f32x4* s4   = (const f32x4*)s2;

    float acc = 0.f;
    #pragma unroll
    for (int j = 0; j < (N_NODES / 4) / 64; ++j) {   // 32 iters
        int idx = j * 64 + lane;
        f32x4 a = arow[idx];
        f32x4 s = s4[idx];
        f32x4 p = a * a * s;
        acc += p.x + p.y + p.z + p.w;
    }
    #pragma unroll
    for (int off = 32; off > 0; off >>= 1) acc += __shfl_xor(acc, off, 64);
    if (lane == 0) r[row] = acc;
}

// Stage 4: out[e] = r[src_nodes[e]]
__global__ void gather_out(const int* __restrict__ src,
                           const float* __restrict__ r,
                           float* __restrict__ out) {
    int e = blockIdx.x * blockDim.x + threadIdx.x;
    if (e < E_EDGES) out[e] = r[src[e]];
}

extern "C" void kernel_launch(void* const* d_in, const int* in_sizes, int n_in,
                              void* d_out, int out_size, void* d_ws, size_t ws_size,
                              hipStream_t stream) {
    const int*   col       = (const int*)d_in[0];
    const float* values    = (const float*)d_in[1];
    const float* adj       = (const float*)d_in[2];
    const int*   src_nodes = (const int*)d_in[3];
    const float* w1e = (const float*)d_in[4];
    const float* b1e = (const float*)d_in[5];
    const float* w2e = (const float*)d_in[6];
    const float* b2e = (const float*)d_in[7];
    const float* w1n = (const float*)d_in[8];
    const float* b1n = (const float*)d_in[9];
    const float* w2n = (const float*)d_in[10];
    const float* b2n = (const float*)d_in[11];
    float* outp = (float*)d_out;

    float* agg = (float*)d_ws;           // N floats
    float* s2g = agg + N_NODES;          // N floats
    float* r   = s2g + N_NODES;          // N floats

    hipMemsetAsync(agg, 0, N_NODES * sizeof(float), stream);
    edge_mlp_scatter<<<NNZV / NTHR, NTHR, 0, stream>>>(col, values, w1e, b1e, w2e, b2e, agg);
    node_mlp_sq<<<N_NODES / NTHR, NTHR, 0, stream>>>(agg, w1n, b1n, w2n, b2n, s2g);
    row_dot_wave<<<N_NODES / 4, NTHR, 0, stream>>>(adj, s2g, r);
    gather_out<<<E_EDGES / NTHR, NTHR, 0, stream>>>(src_nodes, r, outp);
}